// Round 7
// baseline (125.882 us; speedup 1.0000x reference)
//
#include <hip/hip_runtime.h>

#define Wd 64
#define Hd 64
#define HWp 4096
#define CIN_ 128
#define COUT_ 128

typedef _Float16 f16;
typedef _Float16 h2    __attribute__((ext_vector_type(2)));
typedef _Float16 f16x8 __attribute__((ext_vector_type(8)));
typedef float f32x4    __attribute__((ext_vector_type(4)));

__device__ inline ushort f2h(float f) {
    f16 h = (f16)f;
    return __builtin_bit_cast(ushort, h);
}
__device__ inline h2 gb(const int4& g, int d) {
    return __builtin_bit_cast(h2, (&g.x)[d]);
}
struct H8 { h2 r[4]; };

// ---------------------------------------------------------------------------
// K_prep (1344 blocks):
//   blk 0..255    : transpose x NCHW f32 -> xt[b][yx][c] f16
//   blk 256..831  : repack main w -> f16 w_t2 in MFMA A-fragment order:
//                   flat = (((s*2+wm)*4+ii)*64+lane)*8+j
//                   o = wm*64+ii*16+(lane&15), c = (s&3)*32+(lane>>4)*8+j,
//                   k = s>>2      (s = tap*4 + c-chunk)
//   blk 832..1343 : offset conv (4 used ch) + bilinear metadata per (b,k,p):
//                   meta = int4{ cy0|cx0<<8|cy1<<16|cx1<<24, w0|w1<<16(f16),
//                                w2|w3<<16(f16), 0 }
// ---------------------------------------------------------------------------
__global__ __launch_bounds__(256) void prep_offsets_kernel(
    const float* __restrict__ x, const float* __restrict__ w,
    const float* __restrict__ w_off, const float* __restrict__ b_off,
    ushort* __restrict__ xt, ushort* __restrict__ w_t2,
    int4* __restrict__ meta)
{
    __shared__ char smem[34816];
    int blk = blockIdx.x;
    int t = threadIdx.x;

    if (blk < 256) {
        ushort* tile = (ushort*)smem;                 // [128][136]
        int b = blk >> 5, yx0 = (blk & 31) << 7;
        const float* xb = x + (size_t)b * CIN_ * HWp + yx0;
        int lanelo = t & 31, grp = t >> 5;
        #pragma unroll
        for (int i = 0; i < 4; i++) {
            int cbase = i * 32 + grp * 4;
            float4 v0 = *(const float4*)(xb + (size_t)(cbase + 0) * HWp + lanelo * 4);
            float4 v1 = *(const float4*)(xb + (size_t)(cbase + 1) * HWp + lanelo * 4);
            float4 v2 = *(const float4*)(xb + (size_t)(cbase + 2) * HWp + lanelo * 4);
            float4 v3 = *(const float4*)(xb + (size_t)(cbase + 3) * HWp + lanelo * 4);
            ushort4 u;
            u.x = f2h(v0.x); u.y = f2h(v1.x); u.z = f2h(v2.x); u.w = f2h(v3.x);
            *(ushort4*)&tile[(lanelo * 4 + 0) * 136 + cbase] = u;
            u.x = f2h(v0.y); u.y = f2h(v1.y); u.z = f2h(v2.y); u.w = f2h(v3.y);
            *(ushort4*)&tile[(lanelo * 4 + 1) * 136 + cbase] = u;
            u.x = f2h(v0.z); u.y = f2h(v1.z); u.z = f2h(v2.z); u.w = f2h(v3.z);
            *(ushort4*)&tile[(lanelo * 4 + 2) * 136 + cbase] = u;
            u.x = f2h(v0.w); u.y = f2h(v1.w); u.z = f2h(v2.w); u.w = f2h(v3.w);
            *(ushort4*)&tile[(lanelo * 4 + 3) * 136 + cbase] = u;
        }
        __syncthreads();
        ushort* dst = xt + ((size_t)b * HWp + yx0) * CIN_;
        int c8 = (t & 15) * 8, yxg = t >> 4;
        #pragma unroll
        for (int i = 0; i < 8; i++) {
            int yxl = i * 16 + yxg;
            int4 v = *(int4*)&tile[yxl * 136 + c8];
            *(int4*)(dst + (size_t)yxl * CIN_ + c8) = v;
        }
    } else if (blk < 832) {
        int i = (blk - 256) * 256 + t;               // 147456 total
        int j    = i & 7;
        int lane = (i >> 3) & 63;
        int ii   = (i >> 9) & 3;
        int wm   = (i >> 11) & 1;
        int s    = i >> 12;
        int o = wm * 64 + ii * 16 + (lane & 15);
        int c = (s & 3) * 32 + (lane >> 4) * 8 + j;
        int k = s >> 2;
        w_t2[i] = f2h(w[o * 1152 + c * 9 + k]);
    } else {
        float* wl   = (float*)smem;                   // 4608 f
        float* part = (float*)(smem + 18432);         // 1024 f
        float* der  = (float*)(smem + 22528);         // 256 f
        int blk2 = blk - 832;
        int b = blk2 >> 6;
        int h = blk2 & 63;

        for (int i = t; i < 4608; i += 256) {
            int j = i / 1152;
            int r = i - j * 1152;                     // c*9 + tap
            wl[r * 4 + j] = w_off[i];
        }
        __syncthreads();

        int pi = t & 63, cc = t >> 6;
        const float* xb = x + (size_t)(b * CIN_ + cc * 32) * HWp;

        int idx9[9];
        float msk9[9];
        #pragma unroll
        for (int dy = 0; dy < 3; dy++) {
            int hy = h + dy - 1;
            int hyc = min(max(hy, 0), Hd - 1);
            bool vr = (hy >= 0) && (hy < Hd);
            #pragma unroll
            for (int dx = 0; dx < 3; dx++) {
                int wx = pi + dx - 1;
                int wxc = min(max(wx, 0), Wd - 1);
                bool v = vr && (wx >= 0) && (wx < Wd);
                idx9[dy * 3 + dx] = hyc * Wd + wxc;
                msk9[dy * 3 + dx] = v ? 1.0f : 0.0f;
            }
        }

        float o0 = 0.f, o1 = 0.f, o2 = 0.f, o3 = 0.f;
        #pragma unroll 2
        for (int c = 0; c < 32; c++) {
            const float* xp = xb + c * HWp;
            const float* wc = &wl[(cc * 32 + c) * 36];
            float xv[9];
            #pragma unroll
            for (int tp = 0; tp < 9; tp++) xv[tp] = xp[idx9[tp]] * msk9[tp];
            #pragma unroll
            for (int tp = 0; tp < 9; tp++) {
                float4 wj = *(const float4*)&wc[tp * 4];
                o0 += xv[tp] * wj.x; o1 += xv[tp] * wj.y;
                o2 += xv[tp] * wj.z; o3 += xv[tp] * wj.w;
            }
        }
        part[t * 4 + 0] = o0;
        part[t * 4 + 1] = o1;
        part[t * 4 + 2] = o2;
        part[t * 4 + 3] = o3;
        __syncthreads();

        if (t < 64) {
            float s0 = b_off[0], s1 = b_off[1], s2 = b_off[2], s3 = b_off[3];
            #pragma unroll
            for (int q = 0; q < 4; q++) {
                s0 += part[(q * 64 + t) * 4 + 0];
                s1 += part[(q * 64 + t) * 4 + 1];
                s2 += part[(q * 64 + t) * 4 + 2];
                s3 += part[(q * 64 + t) * 4 + 3];
            }
            der[t * 4 + 0] = s0;
            der[t * 4 + 1] = s1;
            der[t * 4 + 2] = fmaxf(s2, 0.f) + 1.f;
            der[t * 4 + 3] = fmaxf(s3, 0.f) + 1.f;
        }
        __syncthreads();

        #pragma unroll
        for (int s = 0; s < 3; s++) {
            int q = t + s * 256;
            if (q < 576) {
                int k = q >> 6;
                int pp = q & 63;
                float sy = der[pp * 4 + 0], sx = der[pp * 4 + 1];
                float sc1 = der[pp * 4 + 2], sc2 = der[pp * 4 + 3];
                int ky = k / 3, kx = k - ky * 3;
                float by = (float)(ky - 1), bx = (float)(kx - 1);
                bool corner = (ky != 1) && (kx != 1);
                bool edge = (ky != 1) ^ (kx != 1);
                float sk = corner ? sc1 : (edge ? sc2 : 0.0f);
                float py = (float)h + by * sk + sy;
                float px = (float)pp + bx * sk + sx;
                float y0f = floorf(py), x0f = floorf(px);
                float wy = py - y0f, wx = px - x0f;
                int y0 = (int)y0f, x0 = (int)x0f;
                int y1 = y0 + 1, x1 = x0 + 1;
                float vy0 = (y0 >= 0 && y0 < Hd) ? 1.f : 0.f;
                float vy1 = (y1 >= 0 && y1 < Hd) ? 1.f : 0.f;
                float vx0 = (x0 >= 0 && x0 < Wd) ? 1.f : 0.f;
                float vx1 = (x1 >= 0 && x1 < Wd) ? 1.f : 0.f;
                int cy0 = min(max(y0, 0), Hd - 1), cy1 = min(max(y1, 0), Hd - 1);
                int cx0 = min(max(x0, 0), Wd - 1), cx1 = min(max(x1, 0), Wd - 1);
                float w0 = (1.f - wy) * (1.f - wx) * vy0 * vx0;
                float w1 = (1.f - wy) * wx * vy0 * vx1;
                float w2 = wy * (1.f - wx) * vy1 * vx0;
                float w3 = wy * wx * vy1 * vx1;
                int4 m;
                m.x = cy0 | (cx0 << 8) | (cy1 << 16) | (cx1 << 24);
                m.y = (int)((unsigned)f2h(w0) | ((unsigned)f2h(w1) << 16));
                m.z = (int)((unsigned)f2h(w2) | ((unsigned)f2h(w3) << 16));
                m.w = 0;
                meta[(b * 9 + k) * HWp + h * Wd + pp] = m;
            }
        }
    }
}

// ---------------------------------------------------------------------------
// K3: fused gather + f16 MFMA GEMM, BK=64 stages, 2 blocks/CU.
// Block = (b, h-row): M=128, N=64, K=1152 in 18 stages of 2x32-c chunks.
// 256 thr = 4 waves (2 wm x 2 ns), wave tile 64x32.
// A staged global->LDS async (width=16); S gathered (NHWC-f16, line-aligned)
// + pk-f16 bilinear combine -> LDS. Double-buffered, 1 barrier per stage.
// LDS 52 KB -> 2 blocks/CU so barrier drains overlap across blocks (m114).
// ---------------------------------------------------------------------------
__global__ __launch_bounds__(256, 2) void deform_gemm_mfma(
    const ushort* __restrict__ xt, const ushort* __restrict__ w_t2,
    const float* __restrict__ bias, const int4* __restrict__ meta,
    float* __restrict__ out)
{
    __shared__ ushort A_lds[2][2][4096];     // [buf][chunk][(wm*4+i)*512+lane*8+j]
    __shared__ ushort S_lds[2][2][64 * 40];  // [buf][chunk][p*40 + c8]

    int t = threadIdx.x;
    int b = blockIdx.x >> 6;
    int h = blockIdx.x & 63;
    int p0 = h << 6;
    const ushort* xtb = xt + (size_t)b * HWp * CIN_;

    int p  = t >> 2;                 // 0..63 position in row
    int c8 = (t & 3) << 3;           // channel offset in 32-chunk

    int wv = t >> 6, lane = t & 63;
    int wm = wv & 1, ns = wv >> 1;   // M-half, N-32-seg (0..1)
    int lm = lane & 15, lq = lane >> 4;

    f32x4 acc[4][2] = {};

    // per-tap gather state for this thread's (p, c8) slot
    const ushort* cbp[4];
    h2 cwp[4];
    auto loadmeta = [&](int k) {
        int4 m = meta[(b * 9 + k) * HWp + p0 + p];
        int cy0 = m.x & 0xff, cx0 = (m.x >> 8) & 0xff;
        int cy1 = (m.x >> 16) & 0xff, cx1 = (m.x >> 24) & 0xff;
        int ry0 = cy0 << 13, ry1 = cy1 << 13;    // cy * Wd * CIN_
        int rx0 = cx0 << 7,  rx1 = cx1 << 7;     // cx * CIN_
        const ushort* base = xtb + c8;
        cbp[0] = base + ry0 + rx0;
        cbp[1] = base + ry0 + rx1;
        cbp[2] = base + ry1 + rx0;
        cbp[3] = base + ry1 + rx1;
        h2 p01 = __builtin_bit_cast(h2, m.y);
        h2 p23 = __builtin_bit_cast(h2, m.z);
        cwp[0] = __builtin_shufflevector(p01, p01, 0, 0);
        cwp[1] = __builtin_shufflevector(p01, p01, 1, 1);
        cwp[2] = __builtin_shufflevector(p23, p23, 0, 0);
        cwp[3] = __builtin_shufflevector(p23, p23, 1, 1);
    };

    // async A staging: stage st covers w_t2 ushorts [st*8192, st*8192+8192)
    auto stageA = [&](int buf, int st) {
        const ushort* src = w_t2 + (size_t)st * 8192;
        #pragma unroll
        for (int cc = 0; cc < 2; cc++)
            #pragma unroll
            for (int r = 0; r < 2; r++) {
                const ushort* g = src + cc * 4096 + (wv * 2 + r) * 512 + lane * 8;
                ushort* l = &A_lds[buf][cc][(wv * 2 + r) * 512];
                __builtin_amdgcn_global_load_lds(
                    (const __attribute__((address_space(1))) unsigned int*)g,
                    (__attribute__((address_space(3))) unsigned int*)l, 16, 0, 0);
            }
    };

    int4 Gc[2][4], Gn[2][4];
    auto issue = [&](int st, int4 G[2][4]) {
        #pragma unroll
        for (int cc = 0; cc < 2; cc++) {
            int q = (2 * st + cc) & 3;
            #pragma unroll
            for (int r = 0; r < 4; r++)
                G[cc][r] = *(const int4*)(cbp[r] + q * 32);
        }
    };
    auto commitS = [&](int buf, const int4 G[2][4]) {
        #pragma unroll
        for (int cc = 0; cc < 2; cc++) {
            H8 tmp;
            #pragma unroll
            for (int d = 0; d < 4; d++) {
                h2 r = gb(G[cc][0], d) * cwp[0];
                r = gb(G[cc][1], d) * cwp[1] + r;
                r = gb(G[cc][2], d) * cwp[2] + r;
                r = gb(G[cc][3], d) * cwp[3] + r;
                tmp.r[d] = r;
            }
            *(int4*)&S_lds[buf][cc][p * 40 + c8] = __builtin_bit_cast(int4, tmp);
        }
    };

    // prologue: stage 0 -> buffer 0
    loadmeta(0);
    issue(0, Gc);
    stageA(0, 0);
    commitS(0, Gc);
    __syncthreads();

    for (int st = 0; st < 18; st++) {
        int cur = st & 1, nb = cur ^ 1;
        bool prod = (st + 1 < 18);
        if (prod) {
            if (((st + 1) & 1) == 0) loadmeta((st + 1) >> 1);
            issue(st + 1, Gn);
            stageA(nb, st + 1);
        }

        #pragma unroll
        for (int cc = 0; cc < 2; cc++) {
            f16x8 af[4], bfr[2];
            #pragma unroll
            for (int i = 0; i < 4; i++)
                af[i] = *(const f16x8*)&A_lds[cur][cc][(wm * 4 + i) * 512 + lane * 8];
            #pragma unroll
            for (int f = 0; f < 2; f++)
                bfr[f] = *(const f16x8*)&S_lds[cur][cc][(ns * 32 + f * 16 + lm) * 40 + lq * 8];
            #pragma unroll
            for (int i = 0; i < 4; i++)
                #pragma unroll
                for (int f = 0; f < 2; f++)
                    acc[i][f] = __builtin_amdgcn_mfma_f32_16x16x32_f16(
                        af[i], bfr[f], acc[i][f], 0, 0, 0);
        }

        if (prod) {
            commitS(nb, Gn);
            #pragma unroll
            for (int cc = 0; cc < 2; cc++)
                #pragma unroll
                for (int r = 0; r < 4; r++) Gc[cc][r] = Gn[cc][r];
        }
        __syncthreads();
    }

    // epilogue: C layout col(p)=lane&15, row(o)=(lane>>4)*4+reg
    #pragma unroll
    for (int i = 0; i < 4; i++) {
        #pragma unroll
        for (int r = 0; r < 4; r++) {
            int o = wm * 64 + i * 16 + lq * 4 + r;
            float bv = bias[o];
            float* orow = out + (size_t)(b * COUT_ + o) * HWp + p0 + ns * 32 + lm;
            #pragma unroll
            for (int f = 0; f < 2; f++)
                orow[f * 16] = acc[i][f][r] + bv;
        }
    }
}

extern "C" void kernel_launch(void* const* d_in, const int* in_sizes, int n_in,
                              void* d_out, int out_size, void* d_ws, size_t ws_size,
                              hipStream_t stream) {
    const float* x     = (const float*)d_in[0];
    const float* w_off = (const float*)d_in[1];
    const float* b_off = (const float*)d_in[2];
    const float* w     = (const float*)d_in[3];
    const float* bias  = (const float*)d_in[4];
    float* out = (float*)d_out;

    char* ws = (char*)d_ws;
    ushort* xt   = (ushort*)ws;                          // 8 MiB (f16 NHWC)
    ushort* w_t2 = (ushort*)(ws + 8388608);              // 294912 B (f16 frag order)
    int4*   meta = (int4*)(ws + 8683520);                // 4.5 MiB (packed)

    prep_offsets_kernel<<<1344, 256, 0, stream>>>(x, w, w_off, b_off,
                                                  xt, w_t2, meta);
    deform_gemm_mfma<<<512, 256, 0, stream>>>(xt, w_t2, bias, meta, out);
}